// Round 11
// baseline (345.643 us; speedup 1.0000x reference)
//
#include <hip/hip_runtime.h>

#define N_NODES 100000
#define N_EDGES 1600000
#define IN_H 18
#define OUT_H 11
#define NCLASS 40
#define NHID 256
// P'/Z1' rows: 16 bf16 = 32B. elems 0..10 features, 11 = dinv (P') / 0 (Z1'), 12..15 pad.

// ---- bucket geometry: 128 nodes/bucket -> LDS-resident accumulator ----
#define BBITS 7
#define BINS 128
#define NB 782                              // ceil(100000/128)
#define NBLK 800
#define CHUNK 2000                          // NBLK*CHUNK == N_EDGES
#define SRC_MASK 0x1FFFF
#define DMASK (BINS - 1)

// ---- bf16 helpers (storage-only quantization, f32 accumulate) ----
__device__ __forceinline__ float bflo(unsigned u) { return __uint_as_float(u << 16); }
__device__ __forceinline__ float bfhi(unsigned u) { return __uint_as_float(u & 0xFFFF0000u); }
__device__ __forceinline__ unsigned bfr(float x) {             // f32 -> bf16 bits, RNE
    unsigned u = __float_as_uint(x);
    return (u + 0x7FFFu + ((u >> 16) & 1u)) >> 16;
}
__device__ __forceinline__ unsigned bfpack(float a, float b) { return bfr(a) | (bfr(b) << 16); }

// 12 LDS f32 atomic adds of one bf16 row (elems 0..11)
__device__ __forceinline__ void lds_acc12(float* a, uint4 w0, uint2 w1) {
    atomicAdd(a + 0,  bflo(w0.x)); atomicAdd(a + 1,  bfhi(w0.x));
    atomicAdd(a + 2,  bflo(w0.y)); atomicAdd(a + 3,  bfhi(w0.y));
    atomicAdd(a + 4,  bflo(w0.z)); atomicAdd(a + 5,  bfhi(w0.z));
    atomicAdd(a + 6,  bflo(w0.w)); atomicAdd(a + 7,  bfhi(w0.w));
    atomicAdd(a + 8,  bflo(w1.x)); atomicAdd(a + 9,  bfhi(w1.x));
    atomicAdd(a + 10, bflo(w1.y)); atomicAdd(a + 11, bfhi(w1.y));
}

// ---------------- K1a: per-block bucket histogram (LDS atomics only) ----------------
__global__ void k_hist(const int* __restrict__ dst, int* __restrict__ bh, int E) {
    __shared__ int h[NB];
    int t = threadIdx.x;
    for (int i = t; i < NB; i += 256) h[i] = 0;
    __syncthreads();
    const int4* d4 = (const int4*)(dst + blockIdx.x * CHUNK);
    for (int i = t; i < CHUNK / 4; i += 256) {
        int4 w = d4[i];
        atomicAdd(&h[w.x >> BBITS], 1);
        atomicAdd(&h[w.y >> BBITS], 1);
        atomicAdd(&h[w.z >> BBITS], 1);
        atomicAdd(&h[w.w >> BBITS], 1);
    }
    __syncthreads();
    for (int i = t; i < NB; i += 256) bh[i * NBLK + blockIdx.x] = h[i];   // [bin][blk]
}

// ---------------- S1: bucket totals ----------------
__global__ void k_btot(const int* __restrict__ bh, int* __restrict__ btot) {
    __shared__ int s[256];
    int b = blockIdx.x, t = threadIdx.x;
    int sum = 0;
    for (int k = t; k < NBLK; k += 256) sum += bh[b * NBLK + k];
    s[t] = sum;
    __syncthreads();
    for (int off = 128; off > 0; off >>= 1) {
        if (t < off) s[t] += s[t + off];
        __syncthreads();
    }
    if (t == 0) btot[b] = s[0];
}

// ---------------- S2+S3 fused: per-(bin,blk) absolute offsets + bstart ----------------
__global__ __launch_bounds__(1024) void k_boff(int* __restrict__ bh,
                                               const int* __restrict__ btot,
                                               int* __restrict__ bstart) {
    __shared__ int s0[1024], s1[1024];
    __shared__ int bt0[1024], bt1[1024];
    int b = blockIdx.x, t = threadIdx.x;
    bt0[t] = (t < NB) ? btot[t] : 0;
    __syncthreads();
    int *c0 = bt0, *c1 = bt1;
    for (int off = 1; off < 1024; off <<= 1) {
        c1[t] = c0[t] + ((t >= off) ? c0[t - off] : 0);
        __syncthreads();
        int* tmp = c0; c0 = c1; c1 = tmp;
    }
    int base = c0[b] - btot[b];              // exclusive prefix = bucket base
    if (t == 0) {
        bstart[b] = base;
        if (b == 0) bstart[NB] = N_EDGES;
    }
    int v = (t < NBLK) ? bh[b * NBLK + t] : 0;
    s0[t] = v;
    __syncthreads();
    int *c = s0, *n = s1;
    for (int off = 1; off < 1024; off <<= 1) {
        n[t] = c[t] + ((t >= off) ? c[t - off] : 0);
        __syncthreads();
        int* tmp = c; c = n; n = tmp;
    }
    if (t < NBLK) bh[b * NBLK + t] = c[t] - v + base;
}

// ---------------- K1c: scatter edges into buckets (LDS cursors, normal stores) ----------------
__global__ void k_bucket(const int* __restrict__ ei, const int* __restrict__ bh,
                         unsigned int* __restrict__ packed, int E) {
    __shared__ int cur[NB];
    int t = threadIdx.x;
    for (int i = t; i < NB; i += 256) cur[i] = bh[i * NBLK + blockIdx.x];
    __syncthreads();
    int base = blockIdx.x * CHUNK;
    const int4* s4 = (const int4*)(ei + base);
    const int4* d4 = (const int4*)(ei + E + base);
    for (int i = t; i < CHUNK / 4; i += 256) {
        int4 s = s4[i];
        int4 d = d4[i];
        int sl;
        sl = atomicAdd(&cur[d.x >> BBITS], 1);
        packed[sl] = ((unsigned)(d.x & DMASK) << 17) | (unsigned)s.x;
        sl = atomicAdd(&cur[d.y >> BBITS], 1);
        packed[sl] = ((unsigned)(d.y & DMASK) << 17) | (unsigned)s.y;
        sl = atomicAdd(&cur[d.z >> BBITS], 1);
        packed[sl] = ((unsigned)(d.z & DMASK) << 17) | (unsigned)s.z;
        sl = atomicAdd(&cur[d.w >> BBITS], 1);
        packed[sl] = ((unsigned)(d.w & DMASK) << 17) | (unsigned)s.w;
    }
}

// ---------------- W12 = W1 @ W2, bb = b1 @ W2 (one block) ----------------
__global__ void k_w12(const float* __restrict__ W1, const float* __restrict__ b1,
                      const float* __restrict__ W2,
                      float* __restrict__ W12, float* __restrict__ bb) {
    int t = threadIdx.x;
    if (t < IN_H * OUT_H) {
        int i = t / OUT_H, j = t % OUT_H;
        float s = 0.f;
        for (int k = 0; k < NHID; ++k) s += W1[i * NHID + k] * W2[k * OUT_H + j];
        W12[t] = s;
    } else if (t < IN_H * OUT_H + OUT_H) {
        int j = t - IN_H * OUT_H;
        float s = 0.f;
        for (int k = 0; k < NHID; ++k) s += b1[k] * W2[k * OUT_H + j];
        bb[j] = s;
    }
}

// ---------------- k_prep: per-bucket degree -> dinv + P' rows (bf16) ----------------
__global__ __launch_bounds__(512)
void k_prep(const unsigned int* __restrict__ packed, const int* __restrict__ bstart,
            const float* __restrict__ X, const float* __restrict__ W12g,
            float* __restrict__ dinv, unsigned int* __restrict__ Pp) {
    __shared__ int hist[BINS];
    __shared__ float sW[IN_H * OUT_H];
    int b = blockIdx.x, t = threadIdx.x;
    if (t < BINS) hist[t] = 0;
    if (t >= BINS && t < BINS + IN_H * OUT_H) sW[t - BINS] = W12g[t - BINS];
    __syncthreads();
    int beg = bstart[b], end = bstart[b + 1];
    for (int i = beg + t; i < end; i += 512)
        atomicAdd(&hist[(packed[i] >> 17) & DMASK], 1);
    __syncthreads();
    if (t < BINS) {
        int node = (b << BBITS) + t;
        if (node < N_NODES) {
            float dv = rsqrtf((float)(hist[t] + 1));
            dinv[node] = dv;
            float x[IN_H];
            const float2* xr = (const float2*)(X + (size_t)node * IN_H);
            #pragma unroll
            for (int k = 0; k < IN_H / 2; ++k) {
                float2 cc = xr[k];
                x[2 * k] = cc.x; x[2 * k + 1] = cc.y;
            }
            float pf[OUT_H];
            #pragma unroll
            for (int j = 0; j < OUT_H; ++j) {
                float s = 0.f;
                #pragma unroll
                for (int k = 0; k < IN_H; ++k) s += x[k] * sW[k * OUT_H + j];
                pf[j] = dv * s;
            }
            unsigned* pr = Pp + (size_t)node * 8;
            ((uint4*)pr)[0] = make_uint4(bfpack(pf[0], pf[1]), bfpack(pf[2], pf[3]),
                                         bfpack(pf[4], pf[5]), bfpack(pf[6], pf[7]));
            ((uint4*)pr)[1] = make_uint4(bfpack(pf[8], pf[9]), bfpack(pf[10], dv), 0u, 0u);
        }
    }
}

// ---------------- k_prop1: edge-parallel gather of P' into LDS -> Z1', r ----------------
__global__ __launch_bounds__(512)
void k_prop1(const unsigned int* __restrict__ packed, const int* __restrict__ bstart,
             const float* __restrict__ dinv, const unsigned int* __restrict__ Pp,
             unsigned int* __restrict__ Z1p, float* __restrict__ rvec) {
    __shared__ float acc[BINS * 12];   // 6 KB
    int b = blockIdx.x, t = threadIdx.x;
    for (int i = t; i < BINS * 12; i += 512) acc[i] = 0.f;
    __syncthreads();
    int beg = bstart[b], end = bstart[b + 1];
    int e = beg + t;
    for (; e + 512 < end; e += 1024) {          // unroll 2: two rows in flight
        unsigned p0 = packed[e], p1 = packed[e + 512];
        const unsigned* r0 = Pp + (size_t)(p0 & SRC_MASK) * 8;
        const unsigned* r1 = Pp + (size_t)(p1 & SRC_MASK) * 8;
        uint4 w00 = ((const uint4*)r0)[0]; uint2 w01 = *(const uint2*)(r0 + 4);
        uint4 w10 = ((const uint4*)r1)[0]; uint2 w11 = *(const uint2*)(r1 + 4);
        lds_acc12(&acc[((p0 >> 17) & DMASK) * 12], w00, w01);
        lds_acc12(&acc[((p1 >> 17) & DMASK) * 12], w10, w11);
    }
    if (e < end) {
        unsigned p = packed[e];
        const unsigned* r = Pp + (size_t)(p & SRC_MASK) * 8;
        uint4 w0 = ((const uint4*)r)[0]; uint2 w1 = *(const uint2*)(r + 4);
        lds_acc12(&acc[((p >> 17) & DMASK) * 12], w0, w1);
    }
    __syncthreads();
    if (t < BINS) {
        int node = (b << BBITS) + t;
        if (node < N_NODES) {
            float dd = dinv[node];
            const unsigned* pr = Pp + (size_t)node * 8;
            uint4 w0 = ((const uint4*)pr)[0]; uint2 w1 = *(const uint2*)(pr + 4);
            float sf[12] = {bflo(w0.x), bfhi(w0.x), bflo(w0.y), bfhi(w0.y),
                            bflo(w0.z), bfhi(w0.z), bflo(w0.w), bfhi(w0.w),
                            bflo(w1.x), bfhi(w1.x), bflo(w1.y), bfhi(w1.y)};
            float z[12];
            #pragma unroll
            for (int j = 0; j < 12; ++j) z[j] = acc[t * 12 + j] + sf[j];   // + self-loop
            float s2 = dd * dd;
            rvec[node] = dd * z[11];            // z[11] = sum dinv[src] + dinv[v]
            unsigned* zr = Z1p + (size_t)node * 8;
            ((uint4*)zr)[0] = make_uint4(bfpack(s2 * z[0], s2 * z[1]), bfpack(s2 * z[2], s2 * z[3]),
                                         bfpack(s2 * z[4], s2 * z[5]), bfpack(s2 * z[6], s2 * z[7]));
            ((uint4*)zr)[1] = make_uint4(bfpack(s2 * z[8], s2 * z[9]), bfpack(s2 * z[10], 0.f), 0u, 0u);
        }
    }
}

// ---------------- k_prop2: edge-parallel gather of Z1' + fused dense epilogue ----------------
__global__ __launch_bounds__(512)
void k_prop2(const unsigned int* __restrict__ packed, const int* __restrict__ bstart,
             const float* __restrict__ dinv, const unsigned int* __restrict__ Z1p,
             const float* __restrict__ rvec, const float* __restrict__ bbg,
             const float* __restrict__ b2g, const float* __restrict__ emb_a,
             const float* __restrict__ Wc, const float* __restrict__ bc,
             float* __restrict__ out) {
    __shared__ float acc[BINS * 12];                   // 6 KB
    __shared__ float sWc[(NCLASS + OUT_H) * NCLASS];   // 8.2 KB
    __shared__ float sbc[NCLASS];
    __shared__ float sbb[OUT_H];
    __shared__ float sb2[OUT_H];
    int b = blockIdx.x, t = threadIdx.x;
    for (int i = t; i < BINS * 12; i += 512) acc[i] = 0.f;
    for (int i = t; i < (NCLASS + OUT_H) * NCLASS; i += 512) sWc[i] = Wc[i];
    if (t < NCLASS) sbc[t] = bc[t];
    if (t < OUT_H) { sbb[t] = bbg[t]; sb2[t] = b2g[t]; }
    __syncthreads();
    int beg = bstart[b], end = bstart[b + 1];
    int e = beg + t;
    for (; e + 512 < end; e += 1024) {
        unsigned p0 = packed[e], p1 = packed[e + 512];
        const unsigned* r0 = Z1p + (size_t)(p0 & SRC_MASK) * 8;
        const unsigned* r1 = Z1p + (size_t)(p1 & SRC_MASK) * 8;
        uint4 w00 = ((const uint4*)r0)[0]; uint2 w01 = *(const uint2*)(r0 + 4);
        uint4 w10 = ((const uint4*)r1)[0]; uint2 w11 = *(const uint2*)(r1 + 4);
        lds_acc12(&acc[((p0 >> 17) & DMASK) * 12], w00, w01);
        lds_acc12(&acc[((p1 >> 17) & DMASK) * 12], w10, w11);
    }
    if (e < end) {
        unsigned p = packed[e];
        const unsigned* r = Z1p + (size_t)(p & SRC_MASK) * 8;
        uint4 w0 = ((const uint4*)r)[0]; uint2 w1 = *(const uint2*)(r + 4);
        lds_acc12(&acc[((p >> 17) & DMASK) * 12], w0, w1);
    }
    __syncthreads();
    // finalize: 4 threads/node, 10 output columns each (512 = 128 nodes x 4)
    int tn = t >> 2, jh = (t & 3) * 10;
    int node = (b << BBITS) + tn;
    if (node < N_NODES) {
        float dd = dinv[node], rv = rvec[node];
        const unsigned* zr = Z1p + (size_t)node * 8;
        uint4 w0 = ((const uint4*)zr)[0]; uint2 w1 = *(const uint2*)(zr + 4);
        float zf[11] = {bflo(w0.x), bfhi(w0.x), bflo(w0.y), bfhi(w0.y),
                        bflo(w0.z), bfhi(w0.z), bflo(w0.w), bfhi(w0.w),
                        bflo(w1.x), bfhi(w1.x), bflo(w1.y)};
        const float* ap = &acc[tn * 12];
        float h[OUT_H];
        #pragma unroll
        for (int f = 0; f < OUT_H; ++f) {
            float tv = dd * (ap[f] + zf[f]) + rv * sbb[f] + sb2[f];
            h[f] = tv > 0.f ? tv : 0.f;         // relu
        }
        float o[10];
        #pragma unroll
        for (int j = 0; j < 10; ++j) o[j] = sbc[jh + j];
        const float4* ea4 = (const float4*)(emb_a + (size_t)node * NCLASS);
        #pragma unroll
        for (int k4 = 0; k4 < NCLASS / 4; ++k4) {
            float4 a = ea4[k4];                 // 4 lanes same addr -> broadcast
            const float* q0 = &sWc[(4 * k4 + 0) * NCLASS + jh];
            const float* q1 = &sWc[(4 * k4 + 1) * NCLASS + jh];
            const float* q2 = &sWc[(4 * k4 + 2) * NCLASS + jh];
            const float* q3 = &sWc[(4 * k4 + 3) * NCLASS + jh];
            #pragma unroll
            for (int j = 0; j < 10; ++j)
                o[j] += a.x * q0[j] + a.y * q1[j] + a.z * q2[j] + a.w * q3[j];
        }
        #pragma unroll
        for (int f = 0; f < OUT_H; ++f) {
            const float* q = &sWc[(NCLASS + f) * NCLASS + jh];
            float hv = h[f];
            #pragma unroll
            for (int j = 0; j < 10; ++j) o[j] += hv * q[j];
        }
        float* orow = out + (size_t)node * NCLASS + jh;   // 4 lanes = 160B contiguous
        #pragma unroll
        for (int j2 = 0; j2 < 5; ++j2)
            *(float2*)(orow + 2 * j2) = make_float2(o[2 * j2], o[2 * j2 + 1]);
    }
}

extern "C" void kernel_launch(void* const* d_in, const int* in_sizes, int n_in,
                              void* d_out, int out_size, void* d_ws, size_t ws_size,
                              hipStream_t stream) {
    const float* X     = (const float*)d_in[0];
    const int*   ei    = (const int*)d_in[1];
    const float* emb_a = (const float*)d_in[2];
    const float* W1    = (const float*)d_in[3];
    const float* b1    = (const float*)d_in[4];
    const float* W2    = (const float*)d_in[5];
    const float* b2    = (const float*)d_in[6];
    const float* Wc    = (const float*)d_in[7];
    const float* bc    = (const float*)d_in[8];
    float* out = (float*)d_out;

    char* ws = (char*)d_ws;
    size_t off = 0;
    auto alloc = [&](size_t nbytes) {
        void* p = (void*)(ws + off);
        off += ((nbytes + 255) / 256) * 256;
        return p;
    };
    // bh (2.5MB) dead after k_bucket -> rvec (400KB) aliases it.
    char* bh_base = (char*)alloc((size_t)NB * NBLK * sizeof(int));
    int*   bh     = (int*)bh_base;
    float* rvec   = (float*)bh_base;
    int*   btot   = (int*)  alloc(NB * sizeof(int));
    int*   bstart = (int*)  alloc((NB + 1) * sizeof(int));
    unsigned int* packed = (unsigned int*)alloc((size_t)N_EDGES * sizeof(unsigned int));
    float* dinv   = (float*)alloc(N_NODES * sizeof(float));
    float* W12    = (float*)alloc(IN_H * OUT_H * sizeof(float));
    float* bb     = (float*)alloc(OUT_H * sizeof(float));
    unsigned int* Pp  = (unsigned int*)alloc((size_t)N_NODES * 32);   // bf16 rows, 3.2 MB
    unsigned int* Z1p = (unsigned int*)alloc((size_t)N_NODES * 32);   // bf16 rows, 3.2 MB

    k_w12   <<<1, 256, 0, stream>>>(W1, b1, W2, W12, bb);
    k_hist  <<<NBLK, 256, 0, stream>>>(ei + N_EDGES, bh, N_EDGES);
    k_btot  <<<NB, 256, 0, stream>>>(bh, btot);
    k_boff  <<<NB, 1024, 0, stream>>>(bh, btot, bstart);
    k_bucket<<<NBLK, 256, 0, stream>>>(ei, bh, packed, N_EDGES);
    k_prep  <<<NB, 512, 0, stream>>>(packed, bstart, X, W12, dinv, Pp);
    k_prop1 <<<NB, 512, 0, stream>>>(packed, bstart, dinv, Pp, Z1p, rvec);
    k_prop2 <<<NB, 512, 0, stream>>>(packed, bstart, dinv, Z1p, rvec, bb, b2, emb_a,
                                     Wc, bc, out);
}

// Round 12
// 107.879 us; speedup vs baseline: 3.2040x; 3.2040x over previous
//
#include <hip/hip_runtime.h>

#define N_NODES 100000
#define N_EDGES 1600000
#define IN_H 18
#define OUT_H 11
#define NCLASS 40
#define NHID 256
// P'/Z1' rows: 16 bf16 elems = 32B. elems 0..10 features, 11 = dinv (P'), 12..15 pad.

// ---- bucket-sort geometry ----
#define BBITS 9
#define BINS 512
#define NB 196                              // ceil(100000/512)
#define NBLK 800
#define CHUNK 2000                          // NBLK*CHUNK == N_EDGES; 2000%4==0
#define SRC_MASK 0x1FFFF

// ---- clang ext_vector types (NT builtins reject HIP_vector_type) ----
typedef float    vfloat4 __attribute__((ext_vector_type(4)));
typedef unsigned vuint2  __attribute__((ext_vector_type(2)));

// ---- bf16 helpers (storage-only quantization, f32 accumulate) ----
__device__ __forceinline__ float bflo(unsigned u) { return __uint_as_float(u << 16); }
__device__ __forceinline__ float bfhi(unsigned u) { return __uint_as_float(u & 0xFFFF0000u); }
__device__ __forceinline__ unsigned bfr(float x) {             // f32 -> bf16 bits, RNE
    unsigned u = __float_as_uint(x);
    return (u + 0x7FFFu + ((u >> 16) & 1u)) >> 16;
}
__device__ __forceinline__ unsigned bfpack(float a, float b) { return bfr(a) | (bfr(b) << 16); }
__device__ __forceinline__ float4 bfunpack4(uint2 w) {
    return make_float4(bflo(w.x), bfhi(w.x), bflo(w.y), bfhi(w.y));
}

// ---------------- K1a: per-block bucket histogram (LDS atomics only) ----------------
__global__ void k_hist(const int* __restrict__ dst, int* __restrict__ bh, int E) {
    __shared__ int h[NB];
    int t = threadIdx.x;
    if (t < NB) h[t] = 0;
    __syncthreads();
    const int4* d4 = (const int4*)(dst + blockIdx.x * CHUNK);
    for (int i = t; i < CHUNK / 4; i += blockDim.x) {
        int4 w = d4[i];
        atomicAdd(&h[w.x >> BBITS], 1);
        atomicAdd(&h[w.y >> BBITS], 1);
        atomicAdd(&h[w.z >> BBITS], 1);
        atomicAdd(&h[w.w >> BBITS], 1);
    }
    __syncthreads();
    if (t < NB) bh[t * NBLK + blockIdx.x] = h[t];   // [bin][blk]
}

// ---------------- S1: bucket totals ----------------
__global__ void k_btot(const int* __restrict__ bh, int* __restrict__ btot) {
    __shared__ int s[256];
    int b = blockIdx.x, t = threadIdx.x;
    int sum = 0;
    for (int k = t; k < NBLK; k += 256) sum += bh[b * NBLK + k];
    s[t] = sum;
    __syncthreads();
    for (int off = 128; off > 0; off >>= 1) {
        if (t < off) s[t] += s[t + off];
        __syncthreads();
    }
    if (t == 0) btot[b] = s[0];
}

// ---------------- S2+S3 fused: per-(bin,blk) absolute offsets + bstart ----------------
__global__ __launch_bounds__(1024) void k_boff(int* __restrict__ bh,
                                               const int* __restrict__ btot,
                                               int* __restrict__ bstart) {
    __shared__ int s0[1024], s1[1024];
    __shared__ int bt0[256], bt1[256];
    int b = blockIdx.x, t = threadIdx.x;
    if (t < 256) bt0[t] = (t < NB) ? btot[t] : 0;
    __syncthreads();
    int* c0 = bt0; int* c1 = bt1;
    for (int off = 1; off < 256; off <<= 1) {
        if (t < 256) c1[t] = c0[t] + ((t >= off) ? c0[t - off] : 0);
        __syncthreads();
        int* tmp = c0; c0 = c1; c1 = tmp;
    }
    int base = c0[b] - btot[b];              // exclusive prefix = bucket base
    if (t == 0) {
        bstart[b] = base;
        if (b == 0) bstart[NB] = N_EDGES;
    }
    int v = (t < NBLK) ? bh[b * NBLK + t] : 0;
    s0[t] = v;
    __syncthreads();
    int* c = s0; int* n = s1;
    for (int off = 1; off < 1024; off <<= 1) {
        n[t] = c[t] + ((t >= off) ? c[t - off] : 0);
        __syncthreads();
        int* tmp = c; c = n; n = tmp;
    }
    if (t < NBLK) bh[b * NBLK + t] = c[t] - v + base;
}

// ---------------- K1c: scatter edges into buckets (LDS cursors, NORMAL stores) ----------------
__global__ void k_bucket(const int* __restrict__ ei, const int* __restrict__ bh,
                         unsigned int* __restrict__ packed, int E) {
    __shared__ int cur[NB];
    int t = threadIdx.x;
    if (t < NB) cur[t] = bh[t * NBLK + blockIdx.x];
    __syncthreads();
    int base = blockIdx.x * CHUNK;
    const int4* s4 = (const int4*)(ei + base);
    const int4* d4 = (const int4*)(ei + E + base);
    for (int i = t; i < CHUNK / 4; i += blockDim.x) {
        int4 s = s4[i];
        int4 d = d4[i];
        int sl;
        sl = atomicAdd(&cur[d.x >> BBITS], 1);
        packed[sl] = ((unsigned)(d.x & (BINS - 1)) << 17) | (unsigned)s.x;
        sl = atomicAdd(&cur[d.y >> BBITS], 1);
        packed[sl] = ((unsigned)(d.y & (BINS - 1)) << 17) | (unsigned)s.y;
        sl = atomicAdd(&cur[d.z >> BBITS], 1);
        packed[sl] = ((unsigned)(d.z & (BINS - 1)) << 17) | (unsigned)s.z;
        sl = atomicAdd(&cur[d.w >> BBITS], 1);
        packed[sl] = ((unsigned)(d.w & (BINS - 1)) << 17) | (unsigned)s.w;
    }
}

// ---------------- W12 = W1 @ W2, bb = b1 @ W2 (one block) ----------------
__global__ void k_w12(const float* __restrict__ W1, const float* __restrict__ b1,
                      const float* __restrict__ W2,
                      float* __restrict__ W12, float* __restrict__ bb) {
    int t = threadIdx.x;
    if (t < IN_H * OUT_H) {
        int i = t / OUT_H, j = t % OUT_H;
        float s = 0.f;
        for (int k = 0; k < NHID; ++k) s += W1[i * NHID + k] * W2[k * OUT_H + j];
        W12[t] = s;
    } else if (t < IN_H * OUT_H + OUT_H) {
        int j = t - IN_H * OUT_H;
        float s = 0.f;
        for (int k = 0; k < NHID; ++k) s += b1[k] * W2[k * OUT_H + j];
        bb[j] = s;
    }
}

// ---------------- K2: per-bucket counting sort -> col, rowptr, dinv, P'(bf16) ----------------
__global__ __launch_bounds__(1024)
void k_sort(const unsigned int* __restrict__ packed, const int* __restrict__ bstart,
            const float* __restrict__ X, const float* __restrict__ W12g,
            int* __restrict__ col, int* __restrict__ rowptr,
            float* __restrict__ dinv, unsigned int* __restrict__ Pp) {
    __shared__ int hist[BINS];
    __shared__ int s0[BINS], s1[BINS];
    __shared__ int cur[BINS];
    __shared__ float sW[IN_H * OUT_H];
    int b = blockIdx.x, t = threadIdx.x;
    int beg = bstart[b], end = bstart[b + 1];
    if (t < BINS) hist[t] = 0;
    if (t >= BINS && t < BINS + IN_H * OUT_H) sW[t - BINS] = W12g[t - BINS];
    __syncthreads();
    for (int i = beg + t; i < end; i += blockDim.x)
        atomicAdd(&hist[packed[i] >> 17], 1);
    __syncthreads();
    if (t < BINS) s0[t] = hist[t];
    __syncthreads();
    int* c = s0; int* n = s1;
    for (int off = 1; off < BINS; off <<= 1) {
        if (t < BINS) n[t] = c[t] + ((t >= off) ? c[t - off] : 0);
        __syncthreads();
        int* tmp = c; c = n; n = tmp;
    }
    if (t < BINS) {
        int excl = c[t] - hist[t];
        int gbase = beg + excl;
        cur[t] = gbase;
        int node = (b << BBITS) + t;
        if (node <= N_NODES) rowptr[node] = gbase;
        if (node < N_NODES)  dinv[node] = rsqrtf((float)(hist[t] + 1));
    }
    __syncthreads();
    for (int i = beg + t; i < end; i += blockDim.x) {
        unsigned p = packed[i];
        int slot = atomicAdd(&cur[p >> 17], 1);
        col[slot] = (int)(p & SRC_MASK);
    }
    // ---- fused P' (bf16 rows, 32B) ----
    int node = (b << BBITS) + t;
    if (t < BINS && node < N_NODES) {
        float dv = rsqrtf((float)(hist[t] + 1));
        float x[IN_H];
        const float2* xr = (const float2*)(X + (size_t)node * IN_H);
        #pragma unroll
        for (int k = 0; k < IN_H / 2; ++k) {
            float2 cc = xr[k];
            x[2 * k] = cc.x; x[2 * k + 1] = cc.y;
        }
        float pf[12];
        #pragma unroll
        for (int j = 0; j < OUT_H; ++j) {
            float s = 0.f;
            #pragma unroll
            for (int k = 0; k < IN_H; ++k) s += x[k] * sW[k * OUT_H + j];
            pf[j] = dv * s;
        }
        pf[11] = dv;                          // dinv folded in as "feature 11"
        uint4* pw = (uint4*)(Pp + (size_t)node * 8);
        pw[0] = make_uint4(bfpack(pf[0], pf[1]), bfpack(pf[2], pf[3]),
                           bfpack(pf[4], pf[5]), bfpack(pf[6], pf[7]));
        pw[1] = make_uint4(bfpack(pf[8], pf[9]), bfpack(pf[10], pf[11]), 0u, 0u);
    }
}

// ---------------- gather pass 1: 8 lanes/node, col-prefetch, NT Z/r stores ----------------
__global__ void k_gather1(const int* __restrict__ rowptr, const int* __restrict__ col,
                          const float* __restrict__ dinv, const unsigned int* __restrict__ Pp,
                          unsigned int* __restrict__ Z1p, float* __restrict__ r, int n) {
    int g = blockIdx.x * blockDim.x + threadIdx.x;
    int v = g >> 3;
    if (v >= n) return;
    int sub  = (g >> 2) & 1;    // edge-quad id
    int lane = g & 3;           // feature quarter
    int beg = rowptr[v], end = rowptr[v + 1];
    int half = (end - beg) >> 1;
    int qbeg = beg + (sub ? half : 0);
    int qend = sub ? end : beg + half;
    float4 acc = make_float4(0.f, 0.f, 0.f, 0.f);
    const uint2* P2 = (const uint2*)Pp;       // 4 uint2 per 32B row
    int e = qbeg;
    if (e + 3 < qend) {
        int i0 = col[e], i1 = col[e + 1], i2 = col[e + 2], i3 = col[e + 3];
        e += 4;
        for (;;) {
            bool more = (e + 3 < qend);
            int j0, j1, j2, j3;
            if (more) {                        // issue next cols before gather wait
                j0 = col[e]; j1 = col[e + 1]; j2 = col[e + 2]; j3 = col[e + 3];
            }
            float4 a0 = bfunpack4(P2[(size_t)i0 * 4 + lane]);
            float4 a1 = bfunpack4(P2[(size_t)i1 * 4 + lane]);
            float4 a2 = bfunpack4(P2[(size_t)i2 * 4 + lane]);
            float4 a3 = bfunpack4(P2[(size_t)i3 * 4 + lane]);
            acc.x += a0.x + a1.x + a2.x + a3.x;
            acc.y += a0.y + a1.y + a2.y + a3.y;
            acc.z += a0.z + a1.z + a2.z + a3.z;
            acc.w += a0.w + a1.w + a2.w + a3.w;
            if (!more) break;
            i0 = j0; i1 = j1; i2 = j2; i3 = j3;
            e += 4;
        }
    }
    for (; e < qend; ++e) {
        float4 a = bfunpack4(P2[(size_t)col[e] * 4 + lane]);
        acc.x += a.x; acc.y += a.y; acc.z += a.z; acc.w += a.w;
    }
    if (!sub) {   // self-loop once
        float4 a = bfunpack4(P2[(size_t)v * 4 + lane]);
        acc.x += a.x; acc.y += a.y; acc.z += a.z; acc.w += a.w;
    }
    acc.x += __shfl_xor(acc.x, 4, 8);
    acc.y += __shfl_xor(acc.y, 4, 8);
    acc.z += __shfl_xor(acc.z, 4, 8);
    acc.w += __shfl_xor(acc.w, 4, 8);
    if (!sub) {
        float dd = dinv[v];
        float s2 = dd * dd;
        vuint2 z;
        z.x = bfpack(s2 * acc.x, s2 * acc.y);
        z.y = bfpack(s2 * acc.z, s2 * acc.w);
        // NT store: written once, read next-kernel from random XCD -> don't thrash Pp's L2
        __builtin_nontemporal_store(z, (vuint2*)Z1p + (size_t)v * 4 + lane);
        if (lane == 2) __builtin_nontemporal_store(dd * acc.w, r + v);
    }
}

// ---------------- gather pass 2 FUSED with dense epilogue: 8 lanes/node ----------------
// NT on emb_a loads (read-once) and out stores (write-once) to keep Z1p L2-resident.
__global__ void k_g2d(const int* __restrict__ rowptr, const int* __restrict__ col,
                      const float* __restrict__ dinv, const unsigned int* __restrict__ Z1p,
                      const float* __restrict__ r, const float* __restrict__ bbg,
                      const float* __restrict__ b2g, const float* __restrict__ emb_a,
                      const float* __restrict__ Wc, const float* __restrict__ bc,
                      float* __restrict__ out, int n) {
    __shared__ float sWc[(NCLASS + OUT_H) * NCLASS];   // 51*40 = 2040
    __shared__ float sbc[NCLASS];
    __shared__ float sbb[16];
    __shared__ float sb2[16];
    for (int t = threadIdx.x; t < (NCLASS + OUT_H) * NCLASS; t += blockDim.x) sWc[t] = Wc[t];
    if (threadIdx.x < NCLASS) sbc[threadIdx.x] = bc[threadIdx.x];
    if (threadIdx.x < 16) {
        sbb[threadIdx.x] = (threadIdx.x < OUT_H) ? bbg[threadIdx.x] : 0.f;
        sb2[threadIdx.x] = (threadIdx.x < OUT_H) ? b2g[threadIdx.x] : 0.f;
    }
    __syncthreads();
    int g = blockIdx.x * blockDim.x + threadIdx.x;
    int v = g >> 3;
    if (v >= n) return;
    int sub   = (g >> 2) & 1;   // edge-quad id
    int lane  = g & 3;          // feature quarter
    int lane8 = g & 7;          // dense j-split id
    int beg = rowptr[v], end = rowptr[v + 1];
    int half = (end - beg) >> 1;
    int qbeg = beg + (sub ? half : 0);
    int qend = sub ? end : beg + half;
    float4 acc = make_float4(0.f, 0.f, 0.f, 0.f);
    const uint2* Z2 = (const uint2*)Z1p;
    int e = qbeg;
    if (e + 3 < qend) {
        int i0 = col[e], i1 = col[e + 1], i2 = col[e + 2], i3 = col[e + 3];
        e += 4;
        for (;;) {
            bool more = (e + 3 < qend);
            int j0, j1, j2, j3;
            if (more) {
                j0 = col[e]; j1 = col[e + 1]; j2 = col[e + 2]; j3 = col[e + 3];
            }
            float4 a0 = bfunpack4(Z2[(size_t)i0 * 4 + lane]);
            float4 a1 = bfunpack4(Z2[(size_t)i1 * 4 + lane]);
            float4 a2 = bfunpack4(Z2[(size_t)i2 * 4 + lane]);
            float4 a3 = bfunpack4(Z2[(size_t)i3 * 4 + lane]);
            acc.x += a0.x + a1.x + a2.x + a3.x;
            acc.y += a0.y + a1.y + a2.y + a3.y;
            acc.z += a0.z + a1.z + a2.z + a3.z;
            acc.w += a0.w + a1.w + a2.w + a3.w;
            if (!more) break;
            i0 = j0; i1 = j1; i2 = j2; i3 = j3;
            e += 4;
        }
    }
    for (; e < qend; ++e) {
        float4 a = bfunpack4(Z2[(size_t)col[e] * 4 + lane]);
        acc.x += a.x; acc.y += a.y; acc.z += a.z; acc.w += a.w;
    }
    if (!sub) {
        float4 a = bfunpack4(Z2[(size_t)v * 4 + lane]);
        acc.x += a.x; acc.y += a.y; acc.z += a.z; acc.w += a.w;
    }
    acc.x += __shfl_xor(acc.x, 4, 8);
    acc.y += __shfl_xor(acc.y, 4, 8);
    acc.z += __shfl_xor(acc.z, 4, 8);
    acc.w += __shfl_xor(acc.w, 4, 8);
    float dd = dinv[v];
    float rv = r[v];
    float af[4] = {acc.x, acc.y, acc.z, acc.w};
    float hloc[4];
    #pragma unroll
    for (int c = 0; c < 4; ++c) {
        int f = 4 * lane + c;                 // f in [0,15]; >=11 is pad (zero biases)
        float tv = dd * af[c] + rv * sbb[f] + sb2[f];
        hloc[c] = tv > 0.f ? tv : 0.f;
    }
    // broadcast the 11 h features within each quad (both quads hold identical hloc)
    float hall[OUT_H];
    #pragma unroll
    for (int f = 0; f < OUT_H; ++f)
        hall[f] = __shfl(hloc[f & 3], f >> 2, 4);
    // j-split dense: lane8 owns output columns [5*lane8, 5*lane8+5)
    const int jb = 5 * lane8;
    float o[5];
    #pragma unroll
    for (int j = 0; j < 5; ++j) o[j] = sbc[jb + j];
    const vfloat4* ea4 = (const vfloat4*)(emb_a + (size_t)v * NCLASS);
    #pragma unroll
    for (int k4 = 0; k4 < NCLASS / 4; ++k4) {
        vfloat4 a = __builtin_nontemporal_load(ea4 + k4);   // read-once stream
        const float* w0 = &sWc[(4 * k4 + 0) * NCLASS + jb];
        const float* w1 = &sWc[(4 * k4 + 1) * NCLASS + jb];
        const float* w2 = &sWc[(4 * k4 + 2) * NCLASS + jb];
        const float* w3 = &sWc[(4 * k4 + 3) * NCLASS + jb];
        #pragma unroll
        for (int j = 0; j < 5; ++j)
            o[j] += a.x * w0[j] + a.y * w1[j] + a.z * w2[j] + a.w * w3[j];
    }
    #pragma unroll
    for (int f = 0; f < OUT_H; ++f) {
        const float* w = &sWc[(NCLASS + f) * NCLASS + jb];
        float hv = hall[f];
        #pragma unroll
        for (int j = 0; j < 5; ++j) o[j] += hv * w[j];
    }
    float* orow = out + (size_t)v * NCLASS + jb;   // 8 lanes write 160B contiguous
    #pragma unroll
    for (int j = 0; j < 5; ++j) __builtin_nontemporal_store(o[j], orow + j);
}

extern "C" void kernel_launch(void* const* d_in, const int* in_sizes, int n_in,
                              void* d_out, int out_size, void* d_ws, size_t ws_size,
                              hipStream_t stream) {
    const float* X     = (const float*)d_in[0];
    const int*   ei    = (const int*)d_in[1];
    const float* emb_a = (const float*)d_in[2];
    const float* W1    = (const float*)d_in[3];
    const float* b1    = (const float*)d_in[4];
    const float* W2    = (const float*)d_in[5];
    const float* b2    = (const float*)d_in[6];
    const float* Wc    = (const float*)d_in[7];
    const float* bc    = (const float*)d_in[8];
    float* out = (float*)d_out;

    char* ws = (char*)d_ws;
    size_t off = 0;
    auto alloc = [&](size_t nbytes) {
        void* p = (void*)(ws + off);
        off += ((nbytes + 255) / 256) * 256;
        return p;
    };
    // bh dead after k_bucket -> rvec aliases it.
    char* bh_base = (char*)alloc((size_t)NB * NBLK * sizeof(int));        // 627 KB
    int*   bh     = (int*)bh_base;
    float* rvec   = (float*)bh_base;
    int*   btot   = (int*)  alloc(NB * sizeof(int));
    int*   bstart = (int*)  alloc((NB + 1) * sizeof(int));
    unsigned int* packed = (unsigned int*)alloc((size_t)N_EDGES * sizeof(unsigned int));
    int*   col    = (int*)  alloc((size_t)N_EDGES * sizeof(int));
    int*   rowptr = (int*)  alloc((N_NODES + 1) * sizeof(int));
    float* dinv   = (float*)alloc(N_NODES * sizeof(float));
    float* W12    = (float*)alloc(IN_H * OUT_H * sizeof(float));
    float* bb     = (float*)alloc(OUT_H * sizeof(float));
    unsigned int* Pp  = (unsigned int*)alloc((size_t)N_NODES * 32);       // bf16 rows, 3.2 MB
    unsigned int* Z1p = (unsigned int*)alloc((size_t)N_NODES * 32);       // bf16 rows, 3.2 MB

    const int B = 256;
    int gN8 = (N_NODES * 8 + B - 1) / B;        // 8 lanes per node

    k_w12    <<<1, B, 0, stream>>>(W1, b1, W2, W12, bb);
    k_hist   <<<NBLK, B, 0, stream>>>(ei + N_EDGES, bh, N_EDGES);
    k_btot   <<<NB, 256, 0, stream>>>(bh, btot);
    k_boff   <<<NB, 1024, 0, stream>>>(bh, btot, bstart);
    k_bucket <<<NBLK, B, 0, stream>>>(ei, bh, packed, N_EDGES);
    k_sort   <<<NB, 1024, 0, stream>>>(packed, bstart, X, W12, col, rowptr, dinv, Pp);
    k_gather1<<<gN8, B, 0, stream>>>(rowptr, col, dinv, Pp, Z1p, rvec, N_NODES);
    k_g2d    <<<gN8, B, 0, stream>>>(rowptr, col, dinv, Z1p, rvec, bb, b2, emb_a,
                                     Wc, bc, out, N_NODES);
}